// Round 1
// baseline (1492.579 us; speedup 1.0000x reference)
//
#include <hip/hip_runtime.h>

#define BB 512
#define LL 1024
#define DD 16
#define HH 64
#define NB 4     // batches per block
#define CH 16    // timestep chunk staged in LDS

__device__ __forceinline__ float sigmoidf_(float x) {
    return __builtin_amdgcn_rcpf(1.0f + __expf(-x));
}
__device__ __forceinline__ float tanhf_(float x) {
    x = fminf(fmaxf(x, -15.0f), 15.0f);
    float e = __expf(2.0f * x);
    return (e - 1.0f) * __builtin_amdgcn_rcpf(e + 1.0f);
}

__global__ __launch_bounds__(256, 1) void brios_main(
    const float* __restrict__ x, const float* __restrict__ dt,
    const float* __restrict__ f_Wih, const float* __restrict__ f_Whh,
    const float* __restrict__ f_bih, const float* __restrict__ f_bhh,
    const float* __restrict__ f_gamma, const float* __restrict__ f_Wout,
    const float* __restrict__ f_bout,
    const float* __restrict__ b_Wih, const float* __restrict__ b_Whh,
    const float* __restrict__ b_bih, const float* __restrict__ b_bhh,
    const float* __restrict__ b_gamma, const float* __restrict__ b_Wout,
    const float* __restrict__ b_bout,
    float* __restrict__ out)
{
    const int tid  = threadIdx.x;
    const int wave = tid >> 6;
    const int lane = tid & 63;
    const int dir  = blockIdx.x >> 7;        // 0 = fwd, 1 = bwd
    const int b0   = (blockIdx.x & 127) * NB;

    const float* Wih  = dir ? b_Wih  : f_Wih;
    const float* Whh  = dir ? b_Whh  : f_Whh;
    const float* bih  = dir ? b_bih  : f_bih;
    const float* bhh  = dir ? b_bhh  : f_bhh;
    const float* Wout = dir ? b_Wout : f_Wout;
    float gam = dir ? b_gamma[0] : f_gamma[0];
    gam = fminf(fmaxf(gam, 1e-4f), 10.0f);
    const float bo = dir ? b_bout[0] : f_bout[0];

    // ---- weights in registers: wave w owns k-slice [16w,16w+16) of Whh,
    // d-slice [4w,4w+4) of Wih; lane j owns output rows j, 64+j, 128+j.
    float whr[16], whz[16], whn[16];
#pragma unroll
    for (int kk = 0; kk < 16; ++kk) {
        int k = wave * 16 + kk;
        whr[kk] = Whh[(      lane) * HH + k];
        whz[kk] = Whh[( 64 + lane) * HH + k];
        whn[kk] = Whh[(128 + lane) * HH + k];
    }
    float wxr[4], wxz[4], wxn[4];
#pragma unroll
    for (int dd = 0; dd < 4; ++dd) {
        int d = wave * 4 + dd;
        wxr[dd] = Wih[(      lane) * DD + d];
        wxz[dd] = Wih[( 64 + lane) * DD + d];
        wxn[dd] = Wih[(128 + lane) * DD + d];
    }
    const float br  = bih[lane]       + bhh[lane];
    const float bz  = bih[64 + lane]  + bhh[64 + lane];
    const float bni = bih[128 + lane];
    const float bnh = bhh[128 + lane];
    const float wo  = Wout[lane];

    __shared__ alignas(16) float sh_h[NB][HH];   // raw h (pre-decay) per batch
    __shared__ float4 sh_part[4][NB][HH];        // [wave][batch][lane] partials
    __shared__ float4 sh_x4[NB][CH][4];          // staged x chunk
    __shared__ float  sh_dt[NB][CH];
    __shared__ float  sh_y[NB][CH];

    sh_h[wave][lane] = 0.0f;
    float h_reg = 0.0f;                          // wave w keeps h of batch b0+w

    const int b_my = b0 + wave;
    float* ydir = out + (size_t)(1 + dir) * (BB * LL);

    for (int c = 0; c < LL / CH; ++c) {
        // ---- stage x, dt for this chunk (wave w stages batch b0+w)
        {
            int i  = lane >> 2;
            int d4 = (lane & 3) * 4;
            int s  = c * CH + i;
            int t  = dir ? (LL - 1 - s) : s;
            float4 xv = *(const float4*)(x + ((size_t)b_my * LL + t) * DD + d4);
            sh_x4[wave][i][lane & 3] = xv;
            if (lane < CH) {
                int s2 = c * CH + lane;
                int t2 = dir ? (LL - 1 - s2) : s2;
                sh_dt[wave][lane] = dt[(size_t)b_my * LL + t2];
            }
        }
        __syncthreads();

        for (int i = 0; i < CH; ++i) {
            // ---- phase 1: every wave accumulates its k/d slice for all 4 batches
#pragma unroll
            for (int bb = 0; bb < NB; ++bb) {
                float dtv = fminf(fmaxf(sh_dt[bb][i], 0.0f), 1e6f);
                float dcy = __expf(-gam * dtv);
                float4 xv = sh_x4[bb][i][wave];
                float qr = wxr[0]*xv.x + wxr[1]*xv.y + wxr[2]*xv.z + wxr[3]*xv.w;
                float qz = wxz[0]*xv.x + wxz[1]*xv.y + wxz[2]*xv.z + wxz[3]*xv.w;
                float qn = wxn[0]*xv.x + wxn[1]*xv.y + wxn[2]*xv.z + wxn[3]*xv.w;
                float pr = 0.0f, pz = 0.0f, pn = 0.0f;
#pragma unroll
                for (int q = 0; q < 4; ++q) {
                    float4 hv = *(const float4*)&sh_h[bb][wave * 16 + q * 4];
                    pr += whr[q*4+0]*hv.x + whr[q*4+1]*hv.y + whr[q*4+2]*hv.z + whr[q*4+3]*hv.w;
                    pz += whz[q*4+0]*hv.x + whz[q*4+1]*hv.y + whz[q*4+2]*hv.z + whz[q*4+3]*hv.w;
                    pn += whn[q*4+0]*hv.x + whn[q*4+1]*hv.y + whn[q*4+2]*hv.z + whn[q*4+3]*hv.w;
                }
                float4 o;
                o.x = qr + dcy * pr;   // r-gate: x-part + decay*h-part
                o.y = qz + dcy * pz;   // z-gate
                o.z = qn;              // n-gate, x part (bias added later)
                o.w = dcy * pn;        // n-gate, h part (r-scaled later)
                sh_part[wave][bb][lane] = o;
            }
            __syncthreads();

            // ---- phase 2: wave w reduces batch b0+w
            {
                float4 p0 = sh_part[0][wave][lane];
                float4 p1 = sh_part[1][wave][lane];
                float4 p2 = sh_part[2][wave][lane];
                float4 p3 = sh_part[3][wave][lane];
                float ar  = p0.x + p1.x + p2.x + p3.x + br;
                float az  = p0.y + p1.y + p2.y + p3.y + bz;
                float ani = p0.z + p1.z + p2.z + p3.z + bni;
                float anh = p0.w + p1.w + p2.w + p3.w + bnh;
                float r = sigmoidf_(ar);
                float z = sigmoidf_(az);
                float n = tanhf_(ani + r * anh);
                float dtv = fminf(fmaxf(sh_dt[wave][i], 0.0f), 1e6f);
                float dcy_own = __expf(-gam * dtv);
                float hbar = dcy_own * h_reg;
                h_reg = (1.0f - z) * n + z * hbar;
                sh_h[wave][lane] = h_reg;
                float v = wo * h_reg;
#pragma unroll
                for (int m = 32; m >= 1; m >>= 1) v += __shfl_xor(v, m, 64);
                if (lane == 0) sh_y[wave][i] = v + bo;
            }
            __syncthreads();
        }

        // ---- flush y for this chunk (coalesced, wave 0 only; safe: all waves
        // passed the last step barrier, and next writes to sh_y happen only
        // after the post-staging barrier below)
        if (wave == 0) {
            int bb = lane >> 4;
            int ii = lane & 15;
            int s  = c * CH + ii;
            int t  = dir ? (LL - 1 - s) : s;
            ydir[(size_t)(b0 + bb) * LL + t] = sh_y[bb][ii];
        }
    }
}

__global__ __launch_bounds__(256) void brios_avg(float* __restrict__ out)
{
    int i = blockIdx.x * blockDim.x + threadIdx.x;
    const int n4 = (BB * LL) / 4;
    if (i < n4) {
        const float4* yf = (const float4*)(out + (size_t)BB * LL);
        const float4* yb = (const float4*)(out + (size_t)2 * BB * LL);
        float4 a = yf[i], b = yb[i];
        float4 r;
        r.x = 0.5f * (a.x + b.x);
        r.y = 0.5f * (a.y + b.y);
        r.z = 0.5f * (a.z + b.z);
        r.w = 0.5f * (a.w + b.w);
        ((float4*)out)[i] = r;
    }
}

extern "C" void kernel_launch(void* const* d_in, const int* in_sizes, int n_in,
                              void* d_out, int out_size, void* d_ws, size_t ws_size,
                              hipStream_t stream) {
    const float* x       = (const float*)d_in[0];
    const float* dt      = (const float*)d_in[1];
    const float* f_Wih   = (const float*)d_in[2];
    const float* f_Whh   = (const float*)d_in[3];
    const float* f_bih   = (const float*)d_in[4];
    const float* f_bhh   = (const float*)d_in[5];
    const float* f_gamma = (const float*)d_in[6];
    const float* f_Wout  = (const float*)d_in[7];
    const float* f_bout  = (const float*)d_in[8];
    const float* b_Wih   = (const float*)d_in[9];
    const float* b_Whh   = (const float*)d_in[10];
    const float* b_bih   = (const float*)d_in[11];
    const float* b_bhh   = (const float*)d_in[12];
    const float* b_gamma = (const float*)d_in[13];
    const float* b_Wout  = (const float*)d_in[14];
    const float* b_bout  = (const float*)d_in[15];
    float* out = (float*)d_out;

    brios_main<<<256, 256, 0, stream>>>(x, dt,
        f_Wih, f_Whh, f_bih, f_bhh, f_gamma, f_Wout, f_bout,
        b_Wih, b_Whh, b_bih, b_bhh, b_gamma, b_Wout, b_bout, out);

    const int n4 = (BB * LL) / 4;
    brios_avg<<<(n4 + 255) / 256, 256, 0, stream>>>(out);
}

// Round 2
// 1004.871 us; speedup vs baseline: 1.4853x; 1.4853x over previous
//
#include <hip/hip_runtime.h>

#define BB 512
#define LL 1024
#define DD 16
#define HH 64
#define CH 64   // timesteps staged per chunk

__device__ __forceinline__ float sigmoidf_(float x) {
    return __builtin_amdgcn_rcpf(1.0f + __expf(-x));
}
__device__ __forceinline__ float tanhf_(float x) {
    x = fminf(fmaxf(x, -15.0f), 15.0f);
    float e = __expf(2.0f * x);
    return (e - 1.0f) * __builtin_amdgcn_rcpf(e + 1.0f);
}
__device__ __forceinline__ float bcast_(float v, int k) {
    return __uint_as_float(__builtin_amdgcn_readlane(__float_as_uint(v), k));
}

// One wave (64 lanes) per (direction, batch) sequence. 1024 blocks of 64
// threads -> 4 blocks/CU = 1 wave/SIMD, so up to 512 VGPR/lane is free.
// Lane j holds Whh rows j, 64+j, 128+j (192 regs) and Wih rows (48 regs);
// h[k] broadcast via v_readlane -> no LDS / no barrier in the step loop.
__global__ __launch_bounds__(64, 1) void brios_main(
    const float* __restrict__ x, const float* __restrict__ dt,
    const float* __restrict__ f_Wih, const float* __restrict__ f_Whh,
    const float* __restrict__ f_bih, const float* __restrict__ f_bhh,
    const float* __restrict__ f_gamma, const float* __restrict__ f_Wout,
    const float* __restrict__ f_bout,
    const float* __restrict__ b_Wih, const float* __restrict__ b_Whh,
    const float* __restrict__ b_bih, const float* __restrict__ b_bhh,
    const float* __restrict__ b_gamma, const float* __restrict__ b_Wout,
    const float* __restrict__ b_bout,
    float* __restrict__ out)
{
    const int lane = threadIdx.x;
    const int dir  = blockIdx.x >> 9;     // 0 = fwd, 1 = bwd
    const int b    = blockIdx.x & 511;

    const float* Wih  = dir ? b_Wih  : f_Wih;
    const float* Whh  = dir ? b_Whh  : f_Whh;
    const float* bih  = dir ? b_bih  : f_bih;
    const float* bhh  = dir ? b_bhh  : f_bhh;
    const float* Wout = dir ? b_Wout : f_Wout;
    float gam = dir ? b_gamma[0] : f_gamma[0];
    gam = fminf(fmaxf(gam, 1e-4f), 10.0f);
    const float bo = dir ? b_bout[0] : f_bout[0];

    // ---- weights in registers
    float wr[HH], wz[HH], wn[HH];
#pragma unroll
    for (int k = 0; k < HH; ++k) {
        wr[k] = Whh[(size_t)(      lane) * HH + k];
        wz[k] = Whh[(size_t)( 64 + lane) * HH + k];
        wn[k] = Whh[(size_t)(128 + lane) * HH + k];
    }
    float xr[DD], xz[DD], xn[DD];
#pragma unroll
    for (int d = 0; d < DD; ++d) {
        xr[d] = Wih[(size_t)(      lane) * DD + d];
        xz[d] = Wih[(size_t)( 64 + lane) * DD + d];
        xn[d] = Wih[(size_t)(128 + lane) * DD + d];
    }
    const float br  = bih[lane]      + bhh[lane];
    const float bz  = bih[64 + lane] + bhh[64 + lane];
    const float bni = bih[128 + lane];
    const float bnh = bhh[128 + lane];
    const float wo  = Wout[lane];

    __shared__ alignas(16) float sh_x[CH * DD];  // 4 KB, staged chunk
    __shared__ float sh_dcy[CH];
    __shared__ float sh_y[CH];

    float h_reg = 0.0f;                          // lane j holds h[j]
    float* yd = out + (size_t)(1 + dir) * (BB * LL);
    float4* sh_x4 = (float4*)sh_x;

    for (int c = 0; c < LL / CH; ++c) {
        const int t_low = dir ? (LL - CH - c * CH) : (c * CH);

        // ---- stage x chunk (coalesced float4), reversed in LDS for bwd
        const float4* gx4 = (const float4*)(x + ((size_t)b * LL + t_low) * DD);
#pragma unroll
        for (int q = 0; q < 4; ++q) {
            int j = q * 64 + lane;
            float4 v = gx4[j];
            int st = j >> 2, qd = j & 3;
            int dst = dir ? ((CH - 1 - st) * 4 + qd) : j;
            sh_x4[dst] = v;
        }
        // ---- stage decay factors (exp precomputed once per step)
        {
            float dtv = dt[(size_t)b * LL + t_low + lane];
            dtv = fminf(fmaxf(dtv, 0.0f), 1e6f);
            int ii = dir ? (CH - 1 - lane) : lane;
            sh_dcy[ii] = __expf(-gam * dtv);
        }
        __syncthreads();

        for (int i = 0; i < CH; ++i) {
            float xv[16];
            const float4* xp = (const float4*)(sh_x + i * DD);
            *(float4*)&xv[0]  = xp[0];
            *(float4*)&xv[4]  = xp[1];
            *(float4*)&xv[8]  = xp[2];
            *(float4*)&xv[12] = xp[3];
            float dcy = sh_dcy[i];

            float ar = br, az = bz, an = bni;
#pragma unroll
            for (int d = 0; d < DD; ++d) {
                ar = fmaf(xr[d], xv[d], ar);
                az = fmaf(xz[d], xv[d], az);
                an = fmaf(xn[d], xv[d], an);
            }
            float hr = 0.0f, hz = 0.0f, hn = 0.0f;
#pragma unroll
            for (int k = 0; k < HH; ++k) {
                float hk = bcast_(h_reg, k);
                hr = fmaf(wr[k], hk, hr);
                hz = fmaf(wz[k], hk, hz);
                hn = fmaf(wn[k], hk, hn);
            }
            ar = fmaf(dcy, hr, ar);
            az = fmaf(dcy, hz, az);
            float hnv = fmaf(dcy, hn, bnh);

            float r = sigmoidf_(ar);
            float z = sigmoidf_(az);
            float n = tanhf_(fmaf(r, hnv, an));
            float hbar = dcy * h_reg;
            h_reg = n + z * (hbar - n);          // (1-z)n + z*hbar

            float v = wo * h_reg;
#pragma unroll
            for (int m = 32; m >= 1; m >>= 1) v += __shfl_xor(v, m, 64);
            sh_y[i] = v + bo;                    // same value, all lanes
        }
        __syncthreads();

        // ---- flush y coalesced (reverse map for bwd)
        {
            int ii = dir ? (CH - 1 - lane) : lane;
            yd[(size_t)b * LL + t_low + lane] = sh_y[ii];
        }
        // next chunk's staging barrier orders sh_y/sh_x reuse
    }
}

__global__ __launch_bounds__(256) void brios_avg(float* __restrict__ out)
{
    int i = blockIdx.x * blockDim.x + threadIdx.x;
    const int n4 = (BB * LL) / 4;
    if (i < n4) {
        const float4* yf = (const float4*)(out + (size_t)BB * LL);
        const float4* yb = (const float4*)(out + (size_t)2 * BB * LL);
        float4 a = yf[i], b = yb[i];
        float4 r;
        r.x = 0.5f * (a.x + b.x);
        r.y = 0.5f * (a.y + b.y);
        r.z = 0.5f * (a.z + b.z);
        r.w = 0.5f * (a.w + b.w);
        ((float4*)out)[i] = r;
    }
}

extern "C" void kernel_launch(void* const* d_in, const int* in_sizes, int n_in,
                              void* d_out, int out_size, void* d_ws, size_t ws_size,
                              hipStream_t stream) {
    const float* x       = (const float*)d_in[0];
    const float* dt      = (const float*)d_in[1];
    const float* f_Wih   = (const float*)d_in[2];
    const float* f_Whh   = (const float*)d_in[3];
    const float* f_bih   = (const float*)d_in[4];
    const float* f_bhh   = (const float*)d_in[5];
    const float* f_gamma = (const float*)d_in[6];
    const float* f_Wout  = (const float*)d_in[7];
    const float* f_bout  = (const float*)d_in[8];
    const float* b_Wih   = (const float*)d_in[9];
    const float* b_Whh   = (const float*)d_in[10];
    const float* b_bih   = (const float*)d_in[11];
    const float* b_bhh   = (const float*)d_in[12];
    const float* b_gamma = (const float*)d_in[13];
    const float* b_Wout  = (const float*)d_in[14];
    const float* b_bout  = (const float*)d_in[15];
    float* out = (float*)d_out;

    brios_main<<<1024, 64, 0, stream>>>(x, dt,
        f_Wih, f_Whh, f_bih, f_bhh, f_gamma, f_Wout, f_bout,
        b_Wih, b_Whh, b_bih, b_bhh, b_gamma, b_Wout, b_bout, out);

    const int n4 = (BB * LL) / 4;
    brios_avg<<<(n4 + 255) / 256, 256, 0, stream>>>(out);
}